// Round 21
// baseline (382.327 us; speedup 1.0000x reference)
//
#include <hip/hip_runtime.h>
#include <hip/hip_bf16.h>

#define BB  16
#define LL1 2048
#define LL2 2048
#define HH  768
#define NT  24   // 768 / 32
#define LCAP 192 // per-row global candidate capacity
#define TCAP 32  // per-row per-128-tile LDS capacity

typedef __attribute__((ext_vector_type(4))) float f32x4;
typedef __attribute__((ext_vector_type(8))) _Float16 f16x8;
typedef __attribute__((ext_vector_type(4))) _Float16 f16x4;

typedef __attribute__((address_space(3))) unsigned int lds_uint;
typedef __attribute__((address_space(1))) const unsigned int glob_uint;
__device__ __forceinline__ void gl_lds16(const void* g, void* l) {
  __builtin_amdgcn_global_load_lds((glob_uint*)g, (lds_uint*)l, 16, 0, 0);
}

// ---------------- fp32 -> fp16 plane ----------------
__global__ __launch_bounds__(256) void k_split16(
    const float* __restrict__ in, _Float16* __restrict__ p, int n4)
{
  int i = blockIdx.x * 256 + threadIdx.x;
  int stride = gridDim.x * 256;
  for (; i < n4; i += stride) {
    f32x4 v = ((const f32x4*)in)[i];
    f16x4 o;
#pragma unroll
    for (int q = 0; q < 4; ++q) o[q] = (_Float16)v[q];
    ((f16x4*)p)[i] = o;
  }
}

// ---------------- transpose wg -> fp16: Wt[n][k] = wg[k][n] ----------------
__global__ __launch_bounds__(256) void k_split_wt16(
    const float* __restrict__ wg, _Float16* __restrict__ wt)
{
  __shared__ float t[32][33];
  const int k0 = blockIdx.y * 32, n0 = blockIdx.x * 32;
  const int tx = threadIdx.x & 31, ty = threadIdx.x >> 5;
#pragma unroll
  for (int r = ty; r < 32; r += 8) t[r][tx] = wg[(size_t)(k0 + r) * HH + n0 + tx];
  __syncthreads();
#pragma unroll
  for (int r = ty; r < 32; r += 8)
    wt[(size_t)(n0 + r) * HH + k0 + tx] = (_Float16)t[tx][r];
}

__global__ __launch_bounds__(256) void k_zero(int* __restrict__ p, int n)
{
  int i = blockIdx.x * 256 + threadIdx.x;
  if (i < n) p[i] = 0;
}

// ======== K-loop: BM=256 x BN=128 x BK=32, 8 waves (4x2), 3-buffer ========
// Counted-vmcnt depth-2 pipeline at 2 blocks/CU (R17, twice-validated).

#define STAGE_SETUP()                                                      \
  size_t goA0, goA1, goB0; int loA0, loA1, loB0;                           \
  {                                                                        \
    int f0 = tid, f1 = 512 + tid;                                          \
    int r0 = f0 >> 2, s0 = f0 & 3, r1 = f1 >> 2, s1 = f1 & 3;              \
    goA0 = (size_t)r0 * HH + (size_t)((s0 ^ (r0 & 3)) * 8);                \
    goA1 = (size_t)r1 * HH + (size_t)((s1 ^ (r1 & 3)) * 8);                \
    loA0 = f0 * 16; loA1 = f1 * 16;                                        \
    int rb = tid >> 2, sb = tid & 3;                                       \
    goB0 = (size_t)rb * HH + (size_t)((sb ^ (rb & 3)) * 8);                \
    loB0 = tid * 16;                                                       \
  }                                                                        \
  int offA[4], offB[4];                                                    \
  _Pragma("unroll")                                                        \
  for (int mi = 0; mi < 4; ++mi) {                                         \
    int r = wm + mi * 16 + fr;                                             \
    offA[mi] = r * 64 + ((l4 * 16) ^ ((r & 3) << 4));                      \
  }                                                                        \
  _Pragma("unroll")                                                        \
  for (int ni = 0; ni < 4; ++ni) {                                         \
    int r = wn + ni * 16 + fr;                                             \
    offB[ni] = r * 64 + ((l4 * 16) ^ ((r & 3) << 4));                      \
  }

#define STG(buf, k0)                                                       \
  gl_lds16(pA + goA0 + (k0), (char*)&sA[buf][0] + loA0);                   \
  gl_lds16(pA + goA1 + (k0), (char*)&sA[buf][0] + loA1);                   \
  gl_lds16(pB + goB0 + (k0), (char*)&sB[buf][0] + loB0);

#define CMP(buf)                                                           \
  {                                                                        \
    f16x8 fa[4], fb[4];                                                    \
    _Pragma("unroll") for (int mi = 0; mi < 4; ++mi)                       \
      fa[mi] = *(const f16x8*)((const char*)&sA[buf][0] + offA[mi]);       \
    _Pragma("unroll") for (int ni = 0; ni < 4; ++ni)                       \
      fb[ni] = *(const f16x8*)((const char*)&sB[buf][0] + offB[ni]);       \
    _Pragma("unroll") for (int mi = 0; mi < 4; ++mi)                       \
      _Pragma("unroll") for (int ni = 0; ni < 4; ++ni)                     \
        acc[mi][ni] = __builtin_amdgcn_mfma_f32_16x16x32_f16(              \
            fa[mi], fb[ni], acc[mi][ni], 0, 0, 0);                         \
  }

#define KLOOP()                                                            \
  STG(0, 0); STG(1, 32);                                                   \
  asm volatile("s_waitcnt vmcnt(3)" ::: "memory");                         \
  __builtin_amdgcn_s_barrier();                                            \
  __builtin_amdgcn_sched_barrier(0);                                       \
  _Pragma("unroll")                                                        \
  for (int t = 0; t < NT; ++t) {                                           \
    if (t + 2 < NT) { STG((t + 2) % 3, (t + 2) * 32); }                    \
    CMP(t % 3);                                                            \
    if (t + 2 < NT) {                                                      \
      asm volatile("s_waitcnt vmcnt(3)" ::: "memory");                     \
    } else {                                                               \
      asm volatile("s_waitcnt vmcnt(0)" ::: "memory");                     \
    }                                                                      \
    __builtin_amdgcn_s_barrier();                                          \
    __builtin_amdgcn_sched_barrier(0);                                     \
  }

// ---------------- K1: G = hi1 @ wg ----------------
__global__ __launch_bounds__(512, 4) void k_gemm_f16(
    const _Float16* __restrict__ A, const _Float16* __restrict__ Bt,
    _Float16* __restrict__ C)
{
  __shared__ _Float16 sA[3][256 * 32], sB[3][128 * 32];   // 72 KB
  const int tid = threadIdx.x, lane = tid & 63, wave = tid >> 6;
  const int wm = (wave >> 1) * 64, wn = (wave & 1) * 64;
  const int m0 = blockIdx.y * 256, n0 = blockIdx.x * 128;
  const int fr = lane & 15, l4 = lane >> 4;
  const _Float16* pA = A  + (size_t)m0 * HH;
  const _Float16* pB = Bt + (size_t)n0 * HH;
  f32x4 acc[4][4] = {};
  STAGE_SETUP();
  KLOOP();

#pragma unroll
  for (int mi = 0; mi < 4; ++mi)
#pragma unroll
    for (int ni = 0; ni < 4; ++ni)
#pragma unroll
      for (int j = 0; j < 4; ++j) {
        int row = m0 + wm + mi * 16 + l4 * 4 + j;
        int col = n0 + wn + ni * 16 + fr;
        C[(size_t)row * HH + col] = (_Float16)acc[mi][ni][j];
      }
}

// ---------------- K2: S = G[b] @ hi2[b]^T -> candidate lists ----------------
// 3-buffer K-loop + tile-threshold LDS compaction (R15/R17 epilogue).
__global__ __launch_bounds__(512, 4) void k_scores_f16(
    const _Float16* __restrict__ G, const _Float16* __restrict__ H2,
    long long* __restrict__ List, int* __restrict__ Cnt, int b_base)
{
  __shared__ char smem[73728];                                       // 72 KB
  _Float16 (*sA)[256 * 32] = (_Float16 (*)[256 * 32])smem;           // 48KB
  _Float16 (*sB)[128 * 32] = (_Float16 (*)[128 * 32])(smem + 49152); // 24KB
  __shared__ float smax[256 * 2];
  __shared__ int lcnt[256], gbase[256];
  const int tid = threadIdx.x, lane = tid & 63, wave = tid >> 6;
  const int wm = (wave >> 1) * 64, wn = (wave & 1) * 64;
  const int z = blockIdx.z, b = b_base + z;
  const int i0 = blockIdx.y * 256, j0 = blockIdx.x * 128;
  const int fr = lane & 15, l4 = lane >> 4;
  const _Float16* pA = G  + (size_t)b * LL1 * HH + (size_t)i0 * HH;
  const _Float16* pB = H2 + (size_t)b * LL2 * HH + (size_t)j0 * HH;
  f32x4 acc[4][4] = {};
  STAGE_SETUP();
  KLOOP();

  // per-row wave-local (64-col) max; combine 2 waves -> 128-col tile rowmax
  if (tid < 256) lcnt[tid] = 0;
#pragma unroll
  for (int mi = 0; mi < 4; ++mi)
#pragma unroll
    for (int j = 0; j < 4; ++j) {
      float rm = fmaxf(fmaxf(acc[mi][0][j], acc[mi][1][j]),
                       fmaxf(acc[mi][2][j], acc[mi][3][j]));
#pragma unroll
      for (int off = 8; off >= 1; off >>= 1) rm = fmaxf(rm, __shfl_xor(rm, off));
      if (fr == 0) smax[(wm + mi * 16 + l4 * 4 + j) * 2 + (wave & 1)] = rm;
    }
  __syncthreads();

  // ballot-compact into per-row LDS lists (lbuf overlays dead K-loop LDS)
  long long* lbuf = (long long*)smem;   // 256 rows x TCAP x 8B = 64KB
#pragma unroll
  for (int mi = 0; mi < 4; ++mi)
#pragma unroll
    for (int j = 0; j < 4; ++j) {
      int rloc = wm + mi * 16 + l4 * 4 + j;
      float thr = fmaxf(smax[rloc * 2], smax[rloc * 2 + 1]) - 20.0f;
#pragma unroll
      for (int ni = 0; ni < 4; ++ni) {
        float val = acc[mi][ni][j];
        bool hit = val > thr;
        unsigned long long mk = __ballot(hit);
        unsigned long long qm = (mk >> (l4 * 16)) & 0xFFFFull;
        if (qm) {
          int base = 0;
          if (fr == 0) base = atomicAdd(&lcnt[rloc], (int)__popcll(qm));
          base = __shfl(base, l4 * 16);
          if (hit) {
            int slot = base + (int)__popcll(qm & ((1ull << fr) - 1ull));
            if (slot < TCAP)
              lbuf[rloc * TCAP + slot] =
                  (((long long)__float_as_int(val)) << 32) |
                  (unsigned int)(j0 + wn + ni * 16 + fr);
          }
        }
      }
    }
  __syncthreads();

  // reserve global space (one atomic per row) and flush
  if (tid < 256) {
    int c = lcnt[tid]; if (c > TCAP) c = TCAP;
    lcnt[tid] = c;
    gbase[tid] = c ? atomicAdd(&Cnt[(size_t)z * LL1 + i0 + tid], c) : 0;
  }
  __syncthreads();
  for (int s = tid; s < 256 * TCAP; s += 512) {
    int r = s >> 5, k = s & 31;
    if (k < lcnt[r]) {
      int gb = gbase[r] + k;
      if (gb < LCAP)
        List[((size_t)z * LL1 + i0 + r) * LCAP + gb] = lbuf[r * TCAP + k];
    }
  }
}

// ---------------- K3: select, canonical column-order (replay-deterministic) ----
// Candidate SET is deterministic; list ORDER is not (atomic races). Process
// candidates in ascending-column order via wave-argmin extraction so lsum/acc
// summation order is canonical -> output bit-stable across graph replays.
__global__ __launch_bounds__(512) void k_select(
    const long long* __restrict__ List, const int* __restrict__ Cnt,
    const _Float16* __restrict__ H2f, float* __restrict__ Out, int b_base)
{
  const int tid = threadIdx.x, lane = tid & 63, wv = tid >> 6;
  const int z = blockIdx.y, b = b_base + z;
  const int row = blockIdx.x * 4 + (wv >> 1);
  const int half = wv & 1;
  const size_t grow = (size_t)z * LL1 + row;
  const _Float16* V = H2f + (size_t)b * LL2 * HH;

  int cnt = Cnt[grow];
  if (cnt > LCAP) cnt = LCAP;

  float sv[3]; int cv[3];
  float m = -1e30f;
#pragma unroll
  for (int q = 0; q < 3; ++q) {
    int i = q * 64 + lane;
    bool valid = i < cnt;
    long long e = valid ? List[grow * LCAP + i] : 0;
    sv[q] = valid ? __int_as_float((int)(e >> 32)) : -1e30f;
    cv[q] = (int)(unsigned int)(e & 0xffffffffLL);
    m = fmaxf(m, sv[q]);
  }
#pragma unroll
  for (int off = 32; off >= 1; off >>= 1) m = fmaxf(m, __shfl_xor(m, off));
  const float thr = m - 20.0f;

  float pv[3]; int rem = 0;
#pragma unroll
  for (int q = 0; q < 3; ++q) {
    bool hit = sv[q] > thr;
    pv[q] = hit ? __expf(sv[q] - m) : 0.f;
    if (hit) rem |= (1 << q);
  }

  float acc[6] = {};
  float lsum = 0.f;
  while (true) {
    // per-lane min column among remaining hits (static q indexing)
    int mycol = 0x7fffffff, myq = -1; float myp = 0.f;
#pragma unroll
    for (int q = 0; q < 3; ++q)
      if ((rem & (1 << q)) && cv[q] < mycol) { mycol = cv[q]; myq = q; myp = pv[q]; }
    // wave min (columns are unique per row -> unique winner lane)
    int wcol = mycol;
#pragma unroll
    for (int off = 32; off >= 1; off >>= 1) {
      int o = __shfl_xor(wcol, off);
      wcol = (o < wcol) ? o : wcol;
    }
    if (wcol == 0x7fffffff) break;
    bool winner = (mycol == wcol);
    unsigned long long wmask = __ballot(winner);
    int src = __ffsll((long long)wmask) - 1;
    float w = __shfl(myp, src);
    if (winner) rem &= ~(1 << myq);
    lsum += w;   // all lanes add identical w in identical order
    const _Float16* vr = V + (size_t)wcol * HH + half * 384;
#pragma unroll
    for (int c = 0; c < 6; ++c) acc[c] = fmaf(w, (float)vr[lane + 64 * c], acc[c]);
  }
  const float inv = 1.0f / lsum;
  float* orow = Out + ((size_t)b * LL1 + row) * HH + half * 384;
#pragma unroll
  for (int c = 0; c < 6; ++c) orow[lane + 64 * c] = acc[c] * inv;
}

extern "C" void kernel_launch(void* const* d_in, const int* in_sizes, int n_in,
                              void* d_out, int out_size, void* d_ws, size_t ws_size,
                              hipStream_t stream) {
  const float* hi1 = (const float*)d_in[0];
  const float* hi2 = (const float*)d_in[1];
  const float* wg  = (const float*)d_in[2];
  float* out = (float*)d_out;

  char* ws = (char*)d_ws;
  const size_t plane_elems = (size_t)BB * LL1 * HH;     // 25.17M
  const size_t plane_b = plane_elems * 2;               // 50.33MB (fp16)
  const size_t wt_b = (size_t)HH * HH * 2;              // 1.18MB
  const size_t list_per_b = (size_t)LL1 * LCAP * 8;     // 3.15MB
  const size_t cnt_per_b  = (size_t)LL1 * 4;            // 8KB

  _Float16* H2f = (_Float16*)ws;
  _Float16* Gf  = (_Float16*)(ws + plane_b);
  _Float16* Wtf = (_Float16*)(ws + 2 * plane_b);
  char* X = ws + 2 * plane_b + wt_b;          // aliased: H1f then List/Cnt
  _Float16* H1f = (_Float16*)X;

  const size_t fixed = 2 * plane_b + wt_b;
  int CB = 1;
  const int cand[5] = {16, 8, 4, 2, 1};
  for (int i = 0; i < 5; ++i) {
    size_t xneed = (size_t)cand[i] * (list_per_b + cnt_per_b);
    if (xneed < plane_b) xneed = plane_b;     // X also holds H1 plane
    if (fixed + xneed + 1024 <= ws_size) { CB = cand[i]; break; }
  }
  long long* List = (long long*)X;
  int* Cnt = (int*)(X + (size_t)CB * list_per_b);

  k_split16<<<4096, 256, 0, stream>>>(hi1, H1f, (int)(plane_elems / 4));
  k_split16<<<4096, 256, 0, stream>>>(hi2, H2f, (int)(plane_elems / 4));
  k_split_wt16<<<dim3(HH / 32, HH / 32), 256, 0, stream>>>(wg, Wtf);

  k_gemm_f16<<<dim3(HH / 128, (BB * LL1) / 256), 512, 0, stream>>>(H1f, Wtf, Gf);

  for (int b0 = 0; b0 < BB; b0 += CB) {
    k_zero<<<(CB * LL1 + 255) / 256, 256, 0, stream>>>(Cnt, CB * LL1);
    k_scores_f16<<<dim3(LL2 / 128, LL1 / 256, CB), 512, 0, stream>>>(
        Gf, H2f, List, Cnt, b0);
    k_select<<<dim3(LL1 / 4, CB), 512, 0, stream>>>(List, Cnt, H2f, out, b0);
  }
}

// Round 22
// 379.633 us; speedup vs baseline: 1.0071x; 1.0071x over previous
//
#include <hip/hip_runtime.h>
#include <hip/hip_bf16.h>

#define BB  16
#define LL1 2048
#define LL2 2048
#define HH  768
#define NT  24   // 768 / 32
#define TCAP 32  // per-row per-128-tile segment capacity (lam~3, P(>=32)~1e-30)

typedef __attribute__((ext_vector_type(4))) float f32x4;
typedef __attribute__((ext_vector_type(8))) _Float16 f16x8;
typedef __attribute__((ext_vector_type(4))) _Float16 f16x4;

typedef __attribute__((address_space(3))) unsigned int lds_uint;
typedef __attribute__((address_space(1))) const unsigned int glob_uint;
__device__ __forceinline__ void gl_lds16(const void* g, void* l) {
  __builtin_amdgcn_global_load_lds((glob_uint*)g, (lds_uint*)l, 16, 0, 0);
}

// ---------------- fp32 -> fp16 plane ----------------
__global__ __launch_bounds__(256) void k_split16(
    const float* __restrict__ in, _Float16* __restrict__ p, int n4)
{
  int i = blockIdx.x * 256 + threadIdx.x;
  int stride = gridDim.x * 256;
  for (; i < n4; i += stride) {
    f32x4 v = ((const f32x4*)in)[i];
    f16x4 o;
#pragma unroll
    for (int q = 0; q < 4; ++q) o[q] = (_Float16)v[q];
    ((f16x4*)p)[i] = o;
  }
}

// ---------------- transpose wg -> fp16: Wt[n][k] = wg[k][n] ----------------
__global__ __launch_bounds__(256) void k_split_wt16(
    const float* __restrict__ wg, _Float16* __restrict__ wt)
{
  __shared__ float t[32][33];
  const int k0 = blockIdx.y * 32, n0 = blockIdx.x * 32;
  const int tx = threadIdx.x & 31, ty = threadIdx.x >> 5;
#pragma unroll
  for (int r = ty; r < 32; r += 8) t[r][tx] = wg[(size_t)(k0 + r) * HH + n0 + tx];
  __syncthreads();
#pragma unroll
  for (int r = ty; r < 32; r += 8)
    wt[(size_t)(n0 + r) * HH + k0 + tx] = (_Float16)t[tx][r];
}

// ======== K-loop: BM=256 x BN=128 x BK=32, 8 waves (4x2), 3-buffer ========
// Counted-vmcnt depth-2 pipeline at 2 blocks/CU (R17, twice-validated).

#define STAGE_SETUP()                                                      \
  size_t goA0, goA1, goB0; int loA0, loA1, loB0;                           \
  {                                                                        \
    int f0 = tid, f1 = 512 + tid;                                          \
    int r0 = f0 >> 2, s0 = f0 & 3, r1 = f1 >> 2, s1 = f1 & 3;              \
    goA0 = (size_t)r0 * HH + (size_t)((s0 ^ (r0 & 3)) * 8);                \
    goA1 = (size_t)r1 * HH + (size_t)((s1 ^ (r1 & 3)) * 8);                \
    loA0 = f0 * 16; loA1 = f1 * 16;                                        \
    int rb = tid >> 2, sb = tid & 3;                                       \
    goB0 = (size_t)rb * HH + (size_t)((sb ^ (rb & 3)) * 8);                \
    loB0 = tid * 16;                                                       \
  }                                                                        \
  int offA[4], offB[4];                                                    \
  _Pragma("unroll")                                                        \
  for (int mi = 0; mi < 4; ++mi) {                                         \
    int r = wm + mi * 16 + fr;                                             \
    offA[mi] = r * 64 + ((l4 * 16) ^ ((r & 3) << 4));                      \
  }                                                                        \
  _Pragma("unroll")                                                        \
  for (int ni = 0; ni < 4; ++ni) {                                         \
    int r = wn + ni * 16 + fr;                                             \
    offB[ni] = r * 64 + ((l4 * 16) ^ ((r & 3) << 4));                      \
  }

#define STG(buf, k0)                                                       \
  gl_lds16(pA + goA0 + (k0), (char*)&sA[buf][0] + loA0);                   \
  gl_lds16(pA + goA1 + (k0), (char*)&sA[buf][0] + loA1);                   \
  gl_lds16(pB + goB0 + (k0), (char*)&sB[buf][0] + loB0);

#define CMP(buf)                                                           \
  {                                                                        \
    f16x8 fa[4], fb[4];                                                    \
    _Pragma("unroll") for (int mi = 0; mi < 4; ++mi)                       \
      fa[mi] = *(const f16x8*)((const char*)&sA[buf][0] + offA[mi]);       \
    _Pragma("unroll") for (int ni = 0; ni < 4; ++ni)                       \
      fb[ni] = *(const f16x8*)((const char*)&sB[buf][0] + offB[ni]);       \
    _Pragma("unroll") for (int mi = 0; mi < 4; ++mi)                       \
      _Pragma("unroll") for (int ni = 0; ni < 4; ++ni)                     \
        acc[mi][ni] = __builtin_amdgcn_mfma_f32_16x16x32_f16(              \
            fa[mi], fb[ni], acc[mi][ni], 0, 0, 0);                         \
  }

#define KLOOP()                                                            \
  STG(0, 0); STG(1, 32);                                                   \
  asm volatile("s_waitcnt vmcnt(3)" ::: "memory");                         \
  __builtin_amdgcn_s_barrier();                                            \
  __builtin_amdgcn_sched_barrier(0);                                       \
  _Pragma("unroll")                                                        \
  for (int t = 0; t < NT; ++t) {                                           \
    if (t + 2 < NT) { STG((t + 2) % 3, (t + 2) * 32); }                    \
    CMP(t % 3);                                                            \
    if (t + 2 < NT) {                                                      \
      asm volatile("s_waitcnt vmcnt(3)" ::: "memory");                     \
    } else {                                                               \
      asm volatile("s_waitcnt vmcnt(0)" ::: "memory");                     \
    }                                                                      \
    __builtin_amdgcn_s_barrier();                                          \
    __builtin_amdgcn_sched_barrier(0);                                     \
  }

// ---------------- K1: G = hi1 @ wg ----------------
__global__ __launch_bounds__(512, 4) void k_gemm_f16(
    const _Float16* __restrict__ A, const _Float16* __restrict__ Bt,
    _Float16* __restrict__ C)
{
  __shared__ _Float16 sA[3][256 * 32], sB[3][128 * 32];   // 72 KB
  const int tid = threadIdx.x, lane = tid & 63, wave = tid >> 6;
  const int wm = (wave >> 1) * 64, wn = (wave & 1) * 64;
  const int m0 = blockIdx.y * 256, n0 = blockIdx.x * 128;
  const int fr = lane & 15, l4 = lane >> 4;
  const _Float16* pA = A  + (size_t)m0 * HH;
  const _Float16* pB = Bt + (size_t)n0 * HH;
  f32x4 acc[4][4] = {};
  STAGE_SETUP();
  KLOOP();

#pragma unroll
  for (int mi = 0; mi < 4; ++mi)
#pragma unroll
    for (int ni = 0; ni < 4; ++ni)
#pragma unroll
      for (int j = 0; j < 4; ++j) {
        int row = m0 + wm + mi * 16 + l4 * 4 + j;
        int col = n0 + wn + ni * 16 + fr;
        C[(size_t)row * HH + col] = (_Float16)acc[mi][ni][j];
      }
}

// ---------------- K2: S = G[b] @ hi2[b]^T -> segmented candidate lists ----
// Deterministic placement, ZERO atomics: two-pass wave-parity-split
// compaction into lbuf, then direct flush to this block's own (row,tile)
// segment: List[(grow*16+tile)*TCAP+k], Cnt16[grow*16+tile]=total.
// Every (row,tile) is written unconditionally -> no zeroing, replay-safe.
__global__ __launch_bounds__(512, 4) void k_scores_f16(
    const _Float16* __restrict__ G, const _Float16* __restrict__ H2,
    long long* __restrict__ List, int* __restrict__ Cnt16, int b_base)
{
  __shared__ char smem[73728];                                       // 72 KB
  _Float16 (*sA)[256 * 32] = (_Float16 (*)[256 * 32])smem;           // 48KB
  _Float16 (*sB)[128 * 32] = (_Float16 (*)[128 * 32])(smem + 49152); // 24KB
  __shared__ float smax[256 * 2];
  __shared__ int cw[256][2];
  const int tid = threadIdx.x, lane = tid & 63, wave = tid >> 6;
  const int wm = (wave >> 1) * 64, wn = (wave & 1) * 64;
  const int z = blockIdx.z, b = b_base + z;
  const int i0 = blockIdx.y * 256, j0 = blockIdx.x * 128;
  const int fr = lane & 15, l4 = lane >> 4;
  const _Float16* pA = G  + (size_t)b * LL1 * HH + (size_t)i0 * HH;
  const _Float16* pB = H2 + (size_t)b * LL2 * HH + (size_t)j0 * HH;
  f32x4 acc[4][4] = {};
  STAGE_SETUP();
  KLOOP();

  // per-row wave-local (64-col) max; combine 2 waves -> 128-col tile rowmax
#pragma unroll
  for (int mi = 0; mi < 4; ++mi)
#pragma unroll
    for (int j = 0; j < 4; ++j) {
      float rm = fmaxf(fmaxf(acc[mi][0][j], acc[mi][1][j]),
                       fmaxf(acc[mi][2][j], acc[mi][3][j]));
#pragma unroll
      for (int off = 8; off >= 1; off >>= 1) rm = fmaxf(rm, __shfl_xor(rm, off));
      if (fr == 0) smax[(wm + mi * 16 + l4 * 4 + j) * 2 + (wave & 1)] = rm;
    }
  __syncthreads();

  // pass 1: per-row per-wave-parity hit counts (pure register math)
#pragma unroll
  for (int mi = 0; mi < 4; ++mi)
#pragma unroll
    for (int j = 0; j < 4; ++j) {
      int rloc = wm + mi * 16 + l4 * 4 + j;
      float thr = fmaxf(smax[rloc * 2], smax[rloc * 2 + 1]) - 20.0f;
      int cnt = 0;
#pragma unroll
      for (int ni = 0; ni < 4; ++ni) {
        bool hit = acc[mi][ni][j] > thr;
        unsigned long long mk = __ballot(hit);
        cnt += (int)__popcll((mk >> (l4 * 16)) & 0xFFFFull);
      }
      if (fr == 0) cw[rloc][wave & 1] = cnt;
    }
  __syncthreads();

  // pass 2: deterministic-slot compaction into lbuf (wave0 first, then wave1;
  // within wave: ni ascending, lane ascending)
  long long* lbuf = (long long*)smem;   // 256 rows x TCAP x 8B = 64KB
#pragma unroll
  for (int mi = 0; mi < 4; ++mi)
#pragma unroll
    for (int j = 0; j < 4; ++j) {
      int rloc = wm + mi * 16 + l4 * 4 + j;
      float thr = fmaxf(smax[rloc * 2], smax[rloc * 2 + 1]) - 20.0f;
      int base = (wave & 1) ? cw[rloc][0] : 0;
#pragma unroll
      for (int ni = 0; ni < 4; ++ni) {
        float val = acc[mi][ni][j];
        bool hit = val > thr;
        unsigned long long mk = __ballot(hit);
        unsigned long long qm = (mk >> (l4 * 16)) & 0xFFFFull;
        if (hit) {
          int slot = base + (int)__popcll(qm & ((1ull << fr) - 1ull));
          if (slot < TCAP)
            lbuf[rloc * TCAP + slot] =
                (((long long)__float_as_int(val)) << 32) |
                (unsigned int)(j0 + wn + ni * 16 + fr);
        }
        base += (int)__popcll(qm);
      }
    }
  __syncthreads();

  // flush: this block owns (rows i0..i0+255, tile j0>>7) exclusively
  const int tile = j0 >> 7;
  if (tid < 256) {
    int tot = cw[tid][0] + cw[tid][1];
    if (tot > TCAP) tot = TCAP;
    cw[tid][0] = tot;
    Cnt16[((size_t)z * LL1 + i0 + tid) * 16 + tile] = tot;
  }
  __syncthreads();
  for (int s = tid; s < 256 * TCAP; s += 512) {
    int r = s >> 5, k = s & 31;
    if (k < cw[r][0])
      List[(((size_t)z * LL1 + i0 + r) * 16 + tile) * TCAP + k] = lbuf[r * TCAP + k];
  }
}

// ---------------- K3: select from segmented lists (deterministic) ----------
// Placement is deterministic -> fixed (q,lane) scan order + per-lane lsum +
// fixed butterfly = bit-stable across replays. 2 waves/row (half split).
__global__ __launch_bounds__(512) void k_select(
    const long long* __restrict__ List, const int* __restrict__ Cnt16,
    const _Float16* __restrict__ H2f, float* __restrict__ Out, int b_base)
{
  const int tid = threadIdx.x, lane = tid & 63, wv = tid >> 6;
  const int z = blockIdx.y, b = b_base + z;
  const int row = blockIdx.x * 4 + (wv >> 1);
  const int half = wv & 1;
  const size_t grow = (size_t)z * LL1 + row;
  const _Float16* V = H2f + (size_t)b * LL2 * HH;

  // round q covers tiles 2q (lanes 0-31) and 2q+1 (lanes 32-63)
  float sv[8]; int cv[8];
  float m = -1e30f;
#pragma unroll
  for (int q = 0; q < 8; ++q) {
    int t = 2 * q + (lane >> 5);
    int slot = lane & 31;
    int c = Cnt16[grow * 16 + t];
    bool valid = slot < c;
    long long e = valid ? List[(grow * 16 + t) * TCAP + slot] : 0;
    sv[q] = valid ? __int_as_float((int)(e >> 32)) : -1e30f;
    cv[q] = (int)(unsigned int)(e & 0xffffffffLL);
    m = fmaxf(m, sv[q]);
  }
#pragma unroll
  for (int off = 32; off >= 1; off >>= 1) m = fmaxf(m, __shfl_xor(m, off));
  const float thr = m - 20.0f;   // exact filter; m = true row max

  float acc[6] = {};
  float lsum = 0.f;
#pragma unroll
  for (int q = 0; q < 8; ++q) {
    bool hit = sv[q] > thr;
    unsigned long long mask = __ballot(hit);
    float p = hit ? __expf(sv[q] - m) : 0.f;
    lsum += p;
    while (mask) {
      int src = __ffsll((long long)mask) - 1;
      mask &= mask - 1;
      float w = __shfl(p, src);
      int jj = __shfl(cv[q], src);
      const _Float16* vr = V + (size_t)jj * HH + half * 384;
#pragma unroll
      for (int c = 0; c < 6; ++c) acc[c] = fmaf(w, (float)vr[lane + 64 * c], acc[c]);
    }
  }
#pragma unroll
  for (int off = 32; off >= 1; off >>= 1) lsum += __shfl_xor(lsum, off);
  const float inv = 1.0f / lsum;
  float* orow = Out + ((size_t)b * LL1 + row) * HH + half * 384;
#pragma unroll
  for (int c = 0; c < 6; ++c) orow[lane + 64 * c] = acc[c] * inv;
}

extern "C" void kernel_launch(void* const* d_in, const int* in_sizes, int n_in,
                              void* d_out, int out_size, void* d_ws, size_t ws_size,
                              hipStream_t stream) {
  const float* hi1 = (const float*)d_in[0];
  const float* hi2 = (const float*)d_in[1];
  const float* wg  = (const float*)d_in[2];
  float* out = (float*)d_out;

  char* ws = (char*)d_ws;
  const size_t plane_elems = (size_t)BB * LL1 * HH;       // 25.17M
  const size_t plane_b = plane_elems * 2;                 // 50.33MB (fp16)
  const size_t wt_b = (size_t)HH * HH * 2;                // 1.18MB
  const size_t list_per_b  = (size_t)LL1 * 16 * TCAP * 8; // 8MB
  const size_t cnt16_per_b = (size_t)LL1 * 16 * 4;        // 128KB

  _Float16* H2f = (_Float16*)ws;
  _Float16* Gf  = (_Float16*)(ws + plane_b);
  _Float16* Wtf = (_Float16*)(ws + 2 * plane_b);
  char* X = ws + 2 * plane_b + wt_b;          // aliased: H1f then List/Cnt16
  _Float16* H1f = (_Float16*)X;

  const size_t fixed = 2 * plane_b + wt_b;
  int CB = 1;
  const int cand[5] = {16, 8, 4, 2, 1};
  for (int i = 0; i < 5; ++i) {
    size_t xneed = (size_t)cand[i] * (list_per_b + cnt16_per_b);
    if (xneed < plane_b) xneed = plane_b;     // X also holds H1 plane
    if (fixed + xneed + 1024 <= ws_size) { CB = cand[i]; break; }
  }
  long long* List = (long long*)X;
  int* Cnt16 = (int*)(X + (size_t)CB * list_per_b);

  k_split16<<<4096, 256, 0, stream>>>(hi1, H1f, (int)(plane_elems / 4));
  k_split16<<<4096, 256, 0, stream>>>(hi2, H2f, (int)(plane_elems / 4));
  k_split_wt16<<<dim3(HH / 32, HH / 32), 256, 0, stream>>>(wg, Wtf);

  k_gemm_f16<<<dim3(HH / 128, (BB * LL1) / 256), 512, 0, stream>>>(H1f, Wtf, Gf);

  for (int b0 = 0; b0 < BB; b0 += CB) {
    k_scores_f16<<<dim3(LL2 / 128, LL1 / 256, CB), 512, 0, stream>>>(
        Gf, H2f, List, Cnt16, b0);
    k_select<<<dim3(LL1 / 4, CB), 512, 0, stream>>>(List, Cnt16, H2f, out, b0);
  }
}

// Round 23
// 350.022 us; speedup vs baseline: 1.0923x; 1.0846x over previous
//
#include <hip/hip_runtime.h>
#include <hip/hip_bf16.h>

#define BB  16
#define LL1 2048
#define LL2 2048
#define HH  768
#define NT  24   // 768 / 32
#define TCAP 32  // per-row per-128-tile segment capacity (lam~3, P(>=32)~1e-30)

typedef __attribute__((ext_vector_type(4))) float f32x4;
typedef __attribute__((ext_vector_type(8))) _Float16 f16x8;
typedef __attribute__((ext_vector_type(4))) _Float16 f16x4;

typedef __attribute__((address_space(3))) unsigned int lds_uint;
typedef __attribute__((address_space(1))) const unsigned int glob_uint;
__device__ __forceinline__ void gl_lds16(const void* g, void* l) {
  __builtin_amdgcn_global_load_lds((glob_uint*)g, (lds_uint*)l, 16, 0, 0);
}

// ---------------- fp32 -> fp16 plane ----------------
__global__ __launch_bounds__(256) void k_split16(
    const float* __restrict__ in, _Float16* __restrict__ p, int n4)
{
  int i = blockIdx.x * 256 + threadIdx.x;
  int stride = gridDim.x * 256;
  for (; i < n4; i += stride) {
    f32x4 v = ((const f32x4*)in)[i];
    f16x4 o;
#pragma unroll
    for (int q = 0; q < 4; ++q) o[q] = (_Float16)v[q];
    ((f16x4*)p)[i] = o;
  }
}

// ---------------- transpose wg -> fp16: Wt[n][k] = wg[k][n] ----------------
__global__ __launch_bounds__(256) void k_split_wt16(
    const float* __restrict__ wg, _Float16* __restrict__ wt)
{
  __shared__ float t[32][33];
  const int k0 = blockIdx.y * 32, n0 = blockIdx.x * 32;
  const int tx = threadIdx.x & 31, ty = threadIdx.x >> 5;
#pragma unroll
  for (int r = ty; r < 32; r += 8) t[r][tx] = wg[(size_t)(k0 + r) * HH + n0 + tx];
  __syncthreads();
#pragma unroll
  for (int r = ty; r < 32; r += 8)
    wt[(size_t)(n0 + r) * HH + k0 + tx] = (_Float16)t[tx][r];
}

// ======== K-loop: BM=256 x BN=128 x BK=32, 8 waves (4x2), 3-buffer ========
// Counted-vmcnt depth-2 pipeline at 2 blocks/CU (R17, twice-validated).

#define STAGE_SETUP()                                                      \
  size_t goA0, goA1, goB0; int loA0, loA1, loB0;                           \
  {                                                                        \
    int f0 = tid, f1 = 512 + tid;                                          \
    int r0 = f0 >> 2, s0 = f0 & 3, r1 = f1 >> 2, s1 = f1 & 3;              \
    goA0 = (size_t)r0 * HH + (size_t)((s0 ^ (r0 & 3)) * 8);                \
    goA1 = (size_t)r1 * HH + (size_t)((s1 ^ (r1 & 3)) * 8);                \
    loA0 = f0 * 16; loA1 = f1 * 16;                                        \
    int rb = tid >> 2, sb = tid & 3;                                       \
    goB0 = (size_t)rb * HH + (size_t)((sb ^ (rb & 3)) * 8);                \
    loB0 = tid * 16;                                                       \
  }                                                                        \
  int offA[4], offB[4];                                                    \
  _Pragma("unroll")                                                        \
  for (int mi = 0; mi < 4; ++mi) {                                         \
    int r = wm + mi * 16 + fr;                                             \
    offA[mi] = r * 64 + ((l4 * 16) ^ ((r & 3) << 4));                      \
  }                                                                        \
  _Pragma("unroll")                                                        \
  for (int ni = 0; ni < 4; ++ni) {                                         \
    int r = wn + ni * 16 + fr;                                             \
    offB[ni] = r * 64 + ((l4 * 16) ^ ((r & 3) << 4));                      \
  }

#define STG(buf, k0)                                                       \
  gl_lds16(pA + goA0 + (k0), (char*)&sA[buf][0] + loA0);                   \
  gl_lds16(pA + goA1 + (k0), (char*)&sA[buf][0] + loA1);                   \
  gl_lds16(pB + goB0 + (k0), (char*)&sB[buf][0] + loB0);

#define CMP(buf)                                                           \
  {                                                                        \
    f16x8 fa[4], fb[4];                                                    \
    _Pragma("unroll") for (int mi = 0; mi < 4; ++mi)                       \
      fa[mi] = *(const f16x8*)((const char*)&sA[buf][0] + offA[mi]);       \
    _Pragma("unroll") for (int ni = 0; ni < 4; ++ni)                       \
      fb[ni] = *(const f16x8*)((const char*)&sB[buf][0] + offB[ni]);       \
    _Pragma("unroll") for (int mi = 0; mi < 4; ++mi)                       \
      _Pragma("unroll") for (int ni = 0; ni < 4; ++ni)                     \
        acc[mi][ni] = __builtin_amdgcn_mfma_f32_16x16x32_f16(              \
            fa[mi], fb[ni], acc[mi][ni], 0, 0, 0);                         \
  }

#define KLOOP()                                                            \
  STG(0, 0); STG(1, 32);                                                   \
  asm volatile("s_waitcnt vmcnt(3)" ::: "memory");                         \
  __builtin_amdgcn_s_barrier();                                            \
  __builtin_amdgcn_sched_barrier(0);                                       \
  _Pragma("unroll")                                                        \
  for (int t = 0; t < NT; ++t) {                                           \
    if (t + 2 < NT) { STG((t + 2) % 3, (t + 2) * 32); }                    \
    CMP(t % 3);                                                            \
    if (t + 2 < NT) {                                                      \
      asm volatile("s_waitcnt vmcnt(3)" ::: "memory");                     \
    } else {                                                               \
      asm volatile("s_waitcnt vmcnt(0)" ::: "memory");                     \
    }                                                                      \
    __builtin_amdgcn_s_barrier();                                          \
    __builtin_amdgcn_sched_barrier(0);                                     \
  }

// ---------------- K1: G = hi1 @ wg ----------------
__global__ __launch_bounds__(512, 4) void k_gemm_f16(
    const _Float16* __restrict__ A, const _Float16* __restrict__ Bt,
    _Float16* __restrict__ C)
{
  __shared__ _Float16 sA[3][256 * 32], sB[3][128 * 32];   // 72 KB
  const int tid = threadIdx.x, lane = tid & 63, wave = tid >> 6;
  const int wm = (wave >> 1) * 64, wn = (wave & 1) * 64;
  const int m0 = blockIdx.y * 256, n0 = blockIdx.x * 128;
  const int fr = lane & 15, l4 = lane >> 4;
  const _Float16* pA = A  + (size_t)m0 * HH;
  const _Float16* pB = Bt + (size_t)n0 * HH;
  f32x4 acc[4][4] = {};
  STAGE_SETUP();
  KLOOP();

#pragma unroll
  for (int mi = 0; mi < 4; ++mi)
#pragma unroll
    for (int ni = 0; ni < 4; ++ni)
#pragma unroll
      for (int j = 0; j < 4; ++j) {
        int row = m0 + wm + mi * 16 + l4 * 4 + j;
        int col = n0 + wn + ni * 16 + fr;
        C[(size_t)row * HH + col] = (_Float16)acc[mi][ni][j];
      }
}

// ---------------- K2: S = G[b] @ hi2[b]^T -> segmented candidate lists ----
// Deterministic placement, ZERO atomics (R22, validated).
__global__ __launch_bounds__(512, 4) void k_scores_f16(
    const _Float16* __restrict__ G, const _Float16* __restrict__ H2,
    long long* __restrict__ List, int* __restrict__ Cnt16, int b_base)
{
  __shared__ char smem[73728];                                       // 72 KB
  _Float16 (*sA)[256 * 32] = (_Float16 (*)[256 * 32])smem;           // 48KB
  _Float16 (*sB)[128 * 32] = (_Float16 (*)[128 * 32])(smem + 49152); // 24KB
  __shared__ float smax[256 * 2];
  __shared__ int cw[256][2];
  const int tid = threadIdx.x, lane = tid & 63, wave = tid >> 6;
  const int wm = (wave >> 1) * 64, wn = (wave & 1) * 64;
  const int z = blockIdx.z, b = b_base + z;
  const int i0 = blockIdx.y * 256, j0 = blockIdx.x * 128;
  const int fr = lane & 15, l4 = lane >> 4;
  const _Float16* pA = G  + (size_t)b * LL1 * HH + (size_t)i0 * HH;
  const _Float16* pB = H2 + (size_t)b * LL2 * HH + (size_t)j0 * HH;
  f32x4 acc[4][4] = {};
  STAGE_SETUP();
  KLOOP();

  // per-row wave-local (64-col) max; combine 2 waves -> 128-col tile rowmax
#pragma unroll
  for (int mi = 0; mi < 4; ++mi)
#pragma unroll
    for (int j = 0; j < 4; ++j) {
      float rm = fmaxf(fmaxf(acc[mi][0][j], acc[mi][1][j]),
                       fmaxf(acc[mi][2][j], acc[mi][3][j]));
#pragma unroll
      for (int off = 8; off >= 1; off >>= 1) rm = fmaxf(rm, __shfl_xor(rm, off));
      if (fr == 0) smax[(wm + mi * 16 + l4 * 4 + j) * 2 + (wave & 1)] = rm;
    }
  __syncthreads();

  // pass 1: per-row per-wave-parity hit counts (pure register math)
#pragma unroll
  for (int mi = 0; mi < 4; ++mi)
#pragma unroll
    for (int j = 0; j < 4; ++j) {
      int rloc = wm + mi * 16 + l4 * 4 + j;
      float thr = fmaxf(smax[rloc * 2], smax[rloc * 2 + 1]) - 20.0f;
      int cnt = 0;
#pragma unroll
      for (int ni = 0; ni < 4; ++ni) {
        bool hit = acc[mi][ni][j] > thr;
        unsigned long long mk = __ballot(hit);
        cnt += (int)__popcll((mk >> (l4 * 16)) & 0xFFFFull);
      }
      if (fr == 0) cw[rloc][wave & 1] = cnt;
    }
  __syncthreads();

  // pass 2: deterministic-slot compaction into lbuf (wave0 first, then wave1;
  // within wave: ni ascending, lane ascending)
  long long* lbuf = (long long*)smem;   // 256 rows x TCAP x 8B = 64KB
#pragma unroll
  for (int mi = 0; mi < 4; ++mi)
#pragma unroll
    for (int j = 0; j < 4; ++j) {
      int rloc = wm + mi * 16 + l4 * 4 + j;
      float thr = fmaxf(smax[rloc * 2], smax[rloc * 2 + 1]) - 20.0f;
      int base = (wave & 1) ? cw[rloc][0] : 0;
#pragma unroll
      for (int ni = 0; ni < 4; ++ni) {
        float val = acc[mi][ni][j];
        bool hit = val > thr;
        unsigned long long mk = __ballot(hit);
        unsigned long long qm = (mk >> (l4 * 16)) & 0xFFFFull;
        if (hit) {
          int slot = base + (int)__popcll(qm & ((1ull << fr) - 1ull));
          if (slot < TCAP)
            lbuf[rloc * TCAP + slot] =
                (((long long)__float_as_int(val)) << 32) |
                (unsigned int)(j0 + wn + ni * 16 + fr);
        }
        base += (int)__popcll(qm);
      }
    }
  __syncthreads();

  // flush: this block owns (rows i0..i0+255, tile j0>>7) exclusively
  const int tile = j0 >> 7;
  if (tid < 256) {
    int tot = cw[tid][0] + cw[tid][1];
    if (tot > TCAP) tot = TCAP;
    cw[tid][0] = tot;
    Cnt16[((size_t)z * LL1 + i0 + tid) * 16 + tile] = tot;
  }
  __syncthreads();
  for (int s = tid; s < 256 * TCAP; s += 512) {
    int r = s >> 5, k = s & 31;
    if (k < cw[r][0])
      List[(((size_t)z * LL1 + i0 + r) * 16 + tile) * TCAP + k] = lbuf[r * TCAP + k];
  }
}

// ---------------- K3: select via in-register rank unranking ----------
// Placement deterministic (R22 scores). Build 16-segment prefix in regs,
// gather candidate rank = q*64+lane directly (dense scan of ~49 entries in
// 3 rounds, 192-rank cap = mean+20sigma). Rank order = (tile,slot) order ->
// bit-stable across replays. No runtime-indexed arrays (rule #20: base
// carried as selected value, pref[] only compile-time-indexed).
__global__ __launch_bounds__(512) void k_select(
    const long long* __restrict__ List, const int* __restrict__ Cnt16,
    const _Float16* __restrict__ H2f, float* __restrict__ Out, int b_base)
{
  const int tid = threadIdx.x, lane = tid & 63, wv = tid >> 6;
  const int z = blockIdx.y, b = b_base + z;
  const int row = blockIdx.x * 4 + (wv >> 1);
  const int half = wv & 1;
  const size_t grow = (size_t)z * LL1 + row;
  const _Float16* V = H2f + (size_t)b * LL2 * HH;

  int pref[16];
  int run = 0;
#pragma unroll
  for (int tt = 0; tt < 16; ++tt) {
    pref[tt] = run;
    run += Cnt16[grow * 16 + tt];   // broadcast loads (uniform addr)
  }
  const int cnt = run;              // ~49 mean; 192-rank cap below

  float sv[3]; int cv[3];
  float m = -1e30f;
#pragma unroll
  for (int q = 0; q < 3; ++q) {
    int rank = q * 64 + lane;
    bool valid = rank < cnt;
    // unrank: tile t = last tt with pref[tt] <= rank; base = pref[t]
    int t = 0, base = 0;
#pragma unroll
    for (int tt = 1; tt < 16; ++tt) {
      bool ge = rank >= pref[tt];
      t = ge ? tt : t;
      base = ge ? pref[tt] : base;
    }
    int slot = rank - base;
    long long e = valid ? List[(grow * 16 + (size_t)t) * TCAP + slot] : 0;
    sv[q] = valid ? __int_as_float((int)(e >> 32)) : -1e30f;
    cv[q] = (int)(unsigned int)(e & 0xffffffffLL);
    m = fmaxf(m, sv[q]);
  }
#pragma unroll
  for (int off = 32; off >= 1; off >>= 1) m = fmaxf(m, __shfl_xor(m, off));
  const float thr = m - 20.0f;   // exact filter; m = true row max

  float acc[6] = {};
  float lsum = 0.f;
#pragma unroll
  for (int q = 0; q < 3; ++q) {
    bool hit = sv[q] > thr;
    unsigned long long mask = __ballot(hit);
    float p = hit ? __expf(sv[q] - m) : 0.f;
    lsum += p;
    while (mask) {
      int src = __ffsll((long long)mask) - 1;
      mask &= mask - 1;
      float w = __shfl(p, src);
      int jj = __shfl(cv[q], src);
      const _Float16* vr = V + (size_t)jj * HH + half * 384;
#pragma unroll
      for (int c = 0; c < 6; ++c) acc[c] = fmaf(w, (float)vr[lane + 64 * c], acc[c]);
    }
  }
#pragma unroll
  for (int off = 32; off >= 1; off >>= 1) lsum += __shfl_xor(lsum, off);
  const float inv = 1.0f / lsum;
  float* orow = Out + ((size_t)b * LL1 + row) * HH + half * 384;
#pragma unroll
  for (int c = 0; c < 6; ++c) orow[lane + 64 * c] = acc[c] * inv;
}

extern "C" void kernel_launch(void* const* d_in, const int* in_sizes, int n_in,
                              void* d_out, int out_size, void* d_ws, size_t ws_size,
                              hipStream_t stream) {
  const float* hi1 = (const float*)d_in[0];
  const float* hi2 = (const float*)d_in[1];
  const float* wg  = (const float*)d_in[2];
  float* out = (float*)d_out;

  char* ws = (char*)d_ws;
  const size_t plane_elems = (size_t)BB * LL1 * HH;       // 25.17M
  const size_t plane_b = plane_elems * 2;                 // 50.33MB (fp16)
  const size_t wt_b = (size_t)HH * HH * 2;                // 1.18MB
  const size_t list_per_b  = (size_t)LL1 * 16 * TCAP * 8; // 8MB
  const size_t cnt16_per_b = (size_t)LL1 * 16 * 4;        // 128KB

  _Float16* H2f = (_Float16*)ws;
  _Float16* Gf  = (_Float16*)(ws + plane_b);
  _Float16* Wtf = (_Float16*)(ws + 2 * plane_b);
  char* X = ws + 2 * plane_b + wt_b;          // aliased: H1f then List/Cnt16
  _Float16* H1f = (_Float16*)X;

  const size_t fixed = 2 * plane_b + wt_b;
  int CB = 1;
  const int cand[5] = {16, 8, 4, 2, 1};
  for (int i = 0; i < 5; ++i) {
    size_t xneed = (size_t)cand[i] * (list_per_b + cnt16_per_b);
    if (xneed < plane_b) xneed = plane_b;     // X also holds H1 plane
    if (fixed + xneed + 1024 <= ws_size) { CB = cand[i]; break; }
  }
  long long* List = (long long*)X;
  int* Cnt16 = (int*)(X + (size_t)CB * list_per_b);

  k_split16<<<4096, 256, 0, stream>>>(hi1, H1f, (int)(plane_elems / 4));
  k_split16<<<4096, 256, 0, stream>>>(hi2, H2f, (int)(plane_elems / 4));
  k_split_wt16<<<dim3(HH / 32, HH / 32), 256, 0, stream>>>(wg, Wtf);

  k_gemm_f16<<<dim3(HH / 128, (BB * LL1) / 256), 512, 0, stream>>>(H1f, Wtf, Gf);

  for (int b0 = 0; b0 < BB; b0 += CB) {
    k_scores_f16<<<dim3(LL2 / 128, LL1 / 256, CB), 512, 0, stream>>>(
        Gf, H2f, List, Cnt16, b0);
    k_select<<<dim3(LL1 / 4, CB), 512, 0, stream>>>(List, Cnt16, H2f, out, b0);
  }
}